// Round 4
// baseline (1759.818 us; speedup 1.0000x reference)
//
#include <hip/hip_runtime.h>
#include <stdint.h>

typedef unsigned short ushort_t;
typedef __attribute__((ext_vector_type(8))) __bf16 bf16x8;
typedef __attribute__((ext_vector_type(4))) float f32x4;

#define B_SZ 16384
#define SEQ 50
#define RAWF 109
#define EMB 20
#define DFEAT 128
#define H 512
#define H4 2048
#define NBLK 10
#define OUTD 20

__device__ __forceinline__ ushort_t f2bf(float f) {
    union { float f; uint32_t u; } v; v.f = f;
    uint32_t r = (v.u + 0x7fffu + ((v.u >> 16) & 1u)) >> 16;
    return (ushort_t)r;
}

// ---------------- weight transpose + bf16 convert ----------------
__global__ __launch_bounds__(256)
void transpose_bf16_kernel(const float* __restrict__ src, ushort_t* __restrict__ dst,
                           int K, int N) {
    __shared__ float tile[32][33];
    const int i = blockIdx.z;
    const float* s = src + (size_t)i * K * N;
    ushort_t* d = dst + (size_t)i * K * N;
    const int tx = threadIdx.x, ty = threadIdx.y; // 32 x 8
    const int k0 = blockIdx.y * 32, n0 = blockIdx.x * 32;
#pragma unroll
    for (int r = 0; r < 4; ++r)
        tile[ty + r * 8][tx] = s[(size_t)(k0 + ty + r * 8) * N + n0 + tx];
    __syncthreads();
#pragma unroll
    for (int r = 0; r < 4; ++r) {
        int n = ty + r * 8;
        d[(size_t)(n0 + n) * K + k0 + tx] = f2bf(tile[tx][n]);
    }
}

// ---------------- seq-len kernel: wave per row ----------------
__global__ __launch_bounds__(256)
void len_kernel(const int* __restrict__ mask, int* __restrict__ len) {
    const int wid = (blockIdx.x * 256 + threadIdx.x) >> 6;
    const int lane = threadIdx.x & 63;
    if (wid >= B_SZ) return;
    int c = (lane < SEQ) ? mask[(size_t)wid * SEQ + lane] : 0;
#pragma unroll
    for (int off = 32; off > 0; off >>= 1) c += __shfl_down(c, off);
    c = __shfl(c, 0);
    if (lane == 0) len[wid] = c;
}

// ---------------- raw-feature kernel: thread = one input column ----------------
__global__ __launch_bounds__(128)
void rawfeat_kernel(const float* __restrict__ inp, const int* __restrict__ len,
                    float* __restrict__ hf, ushort_t* __restrict__ hb,
                    int* __restrict__ ids) {
    const int b = blockIdx.x;
    const int jj = threadIdx.x;
    const float* src = inp + (size_t)b * SEQ * RAWF;
    const int L = len[b];
    const bool active = jj < RAWF;
    float sum = 0.f, mx = -3.0e38f, mn = 3.0e38f, nxt = 0.f;
#pragma unroll 5
    for (int s = 0; s < SEQ; ++s) {
        float v = active ? src[s * RAWF + jj] : 0.f;
        if (s < L) { sum += v; mx = fmaxf(mx, v); mn = fminf(mn, v); }
        if (s == SEQ - 1) nxt = v;
        if (jj == 0) ids[(size_t)b * SEQ + s] = (int)v;
    }
    if (jj >= 1 && jj < RAWF) {
        const int j = 19 + jj;
        const float avg = sum / (float)L;
        mx = fminf(fmaxf(mx, 1e-9f), 1e9f);
        mn = fminf(fmaxf(mn, 1e-9f), 1e9f);
        const size_t base = (size_t)b * H;
        hf[base + j] = avg;             hb[base + j] = f2bf(avg);
        hf[base + DFEAT + j] = mx;      hb[base + DFEAT + j] = f2bf(mx);
        hf[base + 2 * DFEAT + j] = mn;  hb[base + 2 * DFEAT + j] = f2bf(mn);
        hf[base + 3 * DFEAT + j] = nxt; hb[base + 3 * DFEAT + j] = f2bf(nxt);
    }
}

// ---------------- embed-feature kernel: 32-lane group per row ----------------
__global__ __launch_bounds__(256)
void embfeat_kernel(const int* __restrict__ ids, const int* __restrict__ len,
                    const float* __restrict__ embed,
                    float* __restrict__ hf, ushort_t* __restrict__ hb) {
    const int x = threadIdx.x & 31;
    const int row = (blockIdx.x * 256 + threadIdx.x) >> 5;
    if (row >= B_SZ) return;
    const int L = len[row];
    const int* idrow = ids + (size_t)row * SEQ;
    const bool act = x < EMB;
    float sum = 0.f, mx = -3.0e38f, mn = 3.0e38f, nxt = 0.f;
#pragma unroll 5
    for (int s = 0; s < SEQ; ++s) {
        const int id = idrow[s];
        const float v = act ? embed[(size_t)id * EMB + x] : 0.f;
        if (s < L) { sum += v; mx = fmaxf(mx, v); mn = fminf(mn, v); }
        if (s == SEQ - 1) nxt = v;
    }
    if (act) {
        const float avg = sum / (float)L;
        mx = fminf(fmaxf(mx, 1e-9f), 1e9f);
        mn = fminf(fmaxf(mn, 1e-9f), 1e9f);
        const size_t base = (size_t)row * H;
        hf[base + x] = avg;             hb[base + x] = f2bf(avg);
        hf[base + DFEAT + x] = mx;      hb[base + DFEAT + x] = f2bf(mx);
        hf[base + 2 * DFEAT + x] = mn;  hb[base + 2 * DFEAT + x] = f2bf(mn);
        hf[base + 3 * DFEAT + x] = nxt; hb[base + 3 * DFEAT + x] = f2bf(nxt);
    }
}

// ---------------- GEMM: C = relu(A(MxK) * Bt(NxK)^T + bias) ----------------
// Tile 256(M) x 128(N), K-slot = 32, 4-slot LDS ring, counted vmcnt (T3+T4).
// 512 threads = 8 waves (4 wm x 2 wn), wave tile 64x64.
// Ring schedule (race-free by construction):
//   iter kt: stage slot (kt+3)&3  [that slot was last READ in iter kt-1,
//            all waves passed the kt-1 barrier before these loads issue]
//            -> ds_read frags(slot kt&3) -> 16 MFMA
//            -> vmcnt(6): slot kt+1 landed, slots kt+2/kt+3 stay in flight
//            -> barrier. Tail drains 6 -> 3 -> 0.
// MODE 0: write bf16 out. MODE 1: hf += relu(...); hb = bf16(hf)
template <int MODE>
__global__ __launch_bounds__(512, 2)
void gemm_kernel(const ushort_t* __restrict__ A, const ushort_t* __restrict__ Bt,
                 const float* __restrict__ bias,
                 ushort_t* __restrict__ outBf,
                 float* __restrict__ hf, ushort_t* __restrict__ hb,
                 int M, int N, int K) {
    __shared__ alignas(16) ushort_t lA[4][256 * 32];   // 64 KB
    __shared__ alignas(16) ushort_t lB[4][128 * 32];   // 32 KB
    const int tid = threadIdx.x;
    const int lane = tid & 63;
    const int w = tid >> 6;          // 0..7
    const int wm = w >> 1;           // 0..3  (64-row band)
    const int wn = w & 1;            // 0..1  (64-col band)

    // XCD-aware bijective swizzle (nwg % 8 == 0 for both shapes)
    const int gx = N >> 7;
    const int nwg = (M >> 8) * gx;
    const int cpx = nwg >> 3;
    const int bid = blockIdx.x;
    const int wg = (bid & 7) * cpx + (bid >> 3);
    const int ntile = wg % gx, mtile = wg / gx;

    const ushort_t* Abase = A + (size_t)mtile * 256 * K;
    const ushort_t* Bbase = Bt + (size_t)ntile * 128 * K;

    f32x4 acc[4][4];
#pragma unroll
    for (int a = 0; a < 4; ++a)
#pragma unroll
        for (int b = 0; b < 4; ++b) acc[a][b] = (f32x4)(0.f);

    // staging geometry: each wave-load covers 16 consecutive rows x 64B.
    // lane -> (row = base + lane>>2, phys 16B col = lane&3); source col is
    // pre-swizzled with the involution s(row) = (row>>1)&3.
    const int rA0 = w * 32 + (lane >> 2);
    const int rA1 = rA0 + 16;
    const int rB  = w * 16 + (lane >> 2);
    const int csrc = (lane & 3) ^ ((lane >> 3) & 3);   // == (lane&3) ^ s(row)
    const ushort_t* gA0 = Abase + (size_t)rA0 * K + csrc * 8;
    const ushort_t* gA1 = Abase + (size_t)rA1 * K + csrc * 8;
    const ushort_t* gB  = Bbase + (size_t)rB  * K + csrc * 8;

    auto stage = [&](int s, int kt) {
        const int koff = kt * 32;
        __builtin_amdgcn_global_load_lds(
            (const __attribute__((address_space(1))) void*)(gA0 + koff),
            (__attribute__((address_space(3))) void*)(lA[s] + (w * 32) * 32),
            16, 0, 0);
        __builtin_amdgcn_global_load_lds(
            (const __attribute__((address_space(1))) void*)(gA1 + koff),
            (__attribute__((address_space(3))) void*)(lA[s] + (w * 32 + 16) * 32),
            16, 0, 0);
        __builtin_amdgcn_global_load_lds(
            (const __attribute__((address_space(1))) void*)(gB + koff),
            (__attribute__((address_space(3))) void*)(lB[s] + (w * 16) * 32),
            16, 0, 0);
    };

    // fragment-read LDS offsets (elements), loop-invariant:
    // row = band + mf*16 + frow; phys col = k16 ^ ((frow>>1)&3)  (band%16==0)
    const int frow = lane & 15;
    const int k16 = lane >> 4;
    const int fcol = (k16 ^ ((frow >> 1) & 3)) * 8;
    int offA[4], offB[4];
#pragma unroll
    for (int mf = 0; mf < 4; ++mf)
        offA[mf] = (wm * 64 + mf * 16 + frow) * 32 + fcol;
#pragma unroll
    for (int nf = 0; nf < 4; ++nf)
        offB[nf] = (wn * 64 + nf * 16 + frow) * 32 + fcol;

    const int nkt = K >> 5;
    stage(0, 0); stage(1, 1); stage(2, 2);           // 9 loads in flight
    asm volatile("s_waitcnt vmcnt(6)" ::: "memory"); // slot 0 landed
    __syncthreads();

    for (int kt = 0; kt < nkt; ++kt) {
        const int cur = kt & 3;
        if (kt + 3 < nkt) stage((kt + 3) & 3, kt + 3);

        bf16x8 af[4], bfr[4];
#pragma unroll
        for (int mf = 0; mf < 4; ++mf)
            af[mf] = *(const bf16x8*)(lA[cur] + offA[mf]);
#pragma unroll
        for (int nf = 0; nf < 4; ++nf)
            bfr[nf] = *(const bf16x8*)(lB[cur] + offB[nf]);

        __builtin_amdgcn_s_setprio(1);
#pragma unroll
        for (int mf = 0; mf < 4; ++mf)
#pragma unroll
            for (int nf = 0; nf < 4; ++nf)
                acc[mf][nf] = __builtin_amdgcn_mfma_f32_16x16x32_bf16(
                    af[mf], bfr[nf], acc[mf][nf], 0, 0, 0);
        __builtin_amdgcn_s_setprio(0);

        if (kt + 1 < nkt) {
            if (kt + 3 < nkt)      { asm volatile("s_waitcnt vmcnt(6)" ::: "memory"); }
            else if (kt + 2 < nkt) { asm volatile("s_waitcnt vmcnt(3)" ::: "memory"); }
            else                   { asm volatile("s_waitcnt vmcnt(0)" ::: "memory"); }
            __syncthreads();
        }
    }

    // epilogue
#pragma unroll
    for (int mf = 0; mf < 4; ++mf)
#pragma unroll
        for (int nf = 0; nf < 4; ++nf) {
            const int row0 = mtile * 256 + wm * 64 + mf * 16 + (lane >> 4) * 4;
            const int col = ntile * 128 + wn * 64 + nf * 16 + (lane & 15);
            const float bcol = bias[col];
#pragma unroll
            for (int jj = 0; jj < 4; ++jj) {
                float v = acc[mf][nf][jj] + bcol;
                v = v > 0.f ? v : 0.f;
                const size_t idx = (size_t)(row0 + jj) * N + col;
                if (MODE == 0) {
                    outBf[idx] = f2bf(v);
                } else {
                    float nh = hf[idx] + v;
                    hf[idx] = nh;
                    hb[idx] = f2bf(nh);
                }
            }
        }
}

// ---------------- final head: out = hf * Wf + bf ----------------
__global__ __launch_bounds__(256)
void final_kernel(const float* __restrict__ hf, const float* __restrict__ Wf,
                  const float* __restrict__ bfv, float* __restrict__ out) {
    const int gid = blockIdx.x * 256 + threadIdx.x;
    if (gid >= B_SZ * OUTD) return;
    const int b = gid / OUTD, o = gid % OUTD;
    const float* hrow = hf + (size_t)b * H;
    float acc = bfv[o];
    for (int k = 0; k < H; ++k) acc += hrow[k] * Wf[k * OUTD + o];
    out[gid] = acc;
}

extern "C" void kernel_launch(void* const* d_in, const int* in_sizes, int n_in,
                              void* d_out, int out_size, void* d_ws, size_t ws_size,
                              hipStream_t stream) {
    const float* inp   = (const float*)d_in[0];
    const int*   mask  = (const int*)d_in[1];
    const float* embed = (const float*)d_in[2];
    const float* W1    = (const float*)d_in[3];
    const float* b1    = (const float*)d_in[4];
    const float* W2    = (const float*)d_in[5];
    const float* b2    = (const float*)d_in[6];
    const float* Wf    = (const float*)d_in[7];
    const float* bfv   = (const float*)d_in[8];
    float* out = (float*)d_out;

    char* ws = (char*)d_ws;
    ushort_t* W1t = (ushort_t*)ws;                         // NBLK*H4*H bf16
    ushort_t* W2t = W1t + (size_t)NBLK * H4 * H;           // NBLK*H*H4 bf16
    float*    hf  = (float*)(W2t + (size_t)NBLK * H * H4); // B*H f32
    ushort_t* hb  = (ushort_t*)(hf + (size_t)B_SZ * H);    // B*H bf16
    ushort_t* T   = hb + (size_t)B_SZ * H;                 // B*H4 bf16 (GEMM1 out)
    // ids/len alias T's storage: consumed before the first GEMM writes T.
    int* ids = (int*)T;                                    // B*SEQ int
    int* lenb = ids + (size_t)B_SZ * SEQ;                  // B int

    transpose_bf16_kernel<<<dim3(H4 / 32, H / 32, NBLK), dim3(32, 8), 0, stream>>>(W1, W1t, H, H4);
    transpose_bf16_kernel<<<dim3(H / 32, H4 / 32, NBLK), dim3(32, 8), 0, stream>>>(W2, W2t, H4, H);

    len_kernel<<<(B_SZ * 64 + 255) / 256, 256, 0, stream>>>(mask, lenb);
    rawfeat_kernel<<<B_SZ, 128, 0, stream>>>(inp, lenb, hf, hb, ids);
    embfeat_kernel<<<(B_SZ * 32 + 255) / 256, 256, 0, stream>>>(ids, lenb, embed, hf, hb);

    for (int i = 0; i < NBLK; ++i) {
        gemm_kernel<0><<<(B_SZ / 256) * (H4 / 128), 512, 0, stream>>>(
            hb, W1t + (size_t)i * H4 * H, b1 + (size_t)i * H4, T, nullptr, nullptr,
            B_SZ, H4, H);
        gemm_kernel<1><<<(B_SZ / 256) * (H / 128), 512, 0, stream>>>(
            T, W2t + (size_t)i * H * H4, b2 + (size_t)i * H, nullptr, hf, hb,
            B_SZ, H, H4);
    }

    final_kernel<<<(B_SZ * OUTD + 255) / 256, 256, 0, stream>>>(hf, Wf, bfv, out);
}

// Round 5
// 1348.714 us; speedup vs baseline: 1.3048x; 1.3048x over previous
//
#include <hip/hip_runtime.h>
#include <stdint.h>

typedef unsigned short ushort_t;
typedef __attribute__((ext_vector_type(8))) __bf16 bf16x8;
typedef __attribute__((ext_vector_type(4))) float f32x4;

#define B_SZ 16384
#define SEQ 50
#define RAWF 109
#define EMB 20
#define DFEAT 128
#define H 512
#define H4 2048
#define NBLK 10
#define OUTD 20

__device__ __forceinline__ ushort_t f2bf(float f) {
    union { float f; uint32_t u; } v; v.f = f;
    uint32_t r = (v.u + 0x7fffu + ((v.u >> 16) & 1u)) >> 16;
    return (ushort_t)r;
}

// ---------------- weight transpose + bf16 convert ----------------
__global__ __launch_bounds__(256)
void transpose_bf16_kernel(const float* __restrict__ src, ushort_t* __restrict__ dst,
                           int K, int N) {
    __shared__ float tile[32][33];
    const int i = blockIdx.z;
    const float* s = src + (size_t)i * K * N;
    ushort_t* d = dst + (size_t)i * K * N;
    const int tx = threadIdx.x, ty = threadIdx.y; // 32 x 8
    const int k0 = blockIdx.y * 32, n0 = blockIdx.x * 32;
#pragma unroll
    for (int r = 0; r < 4; ++r)
        tile[ty + r * 8][tx] = s[(size_t)(k0 + ty + r * 8) * N + n0 + tx];
    __syncthreads();
#pragma unroll
    for (int r = 0; r < 4; ++r) {
        int n = ty + r * 8;
        d[(size_t)(n0 + n) * K + k0 + tx] = f2bf(tile[tx][n]);
    }
}

// ---------------- seq-len kernel: wave per row ----------------
__global__ __launch_bounds__(256)
void len_kernel(const int* __restrict__ mask, int* __restrict__ len) {
    const int wid = (blockIdx.x * 256 + threadIdx.x) >> 6;
    const int lane = threadIdx.x & 63;
    if (wid >= B_SZ) return;
    int c = (lane < SEQ) ? mask[(size_t)wid * SEQ + lane] : 0;
#pragma unroll
    for (int off = 32; off > 0; off >>= 1) c += __shfl_down(c, off);
    c = __shfl(c, 0);
    if (lane == 0) len[wid] = c;
}

// ---------------- raw-feature kernel: thread = one input column ----------------
__global__ __launch_bounds__(128)
void rawfeat_kernel(const float* __restrict__ inp, const int* __restrict__ len,
                    float* __restrict__ hf, ushort_t* __restrict__ hb,
                    int* __restrict__ ids) {
    const int b = blockIdx.x;
    const int jj = threadIdx.x;
    const float* src = inp + (size_t)b * SEQ * RAWF;
    const int L = len[b];
    const bool active = jj < RAWF;
    float sum = 0.f, mx = -3.0e38f, mn = 3.0e38f, nxt = 0.f;
#pragma unroll 5
    for (int s = 0; s < SEQ; ++s) {
        float v = active ? src[s * RAWF + jj] : 0.f;
        if (s < L) { sum += v; mx = fmaxf(mx, v); mn = fminf(mn, v); }
        if (s == SEQ - 1) nxt = v;
        if (jj == 0) ids[(size_t)b * SEQ + s] = (int)v;
    }
    if (jj >= 1 && jj < RAWF) {
        const int j = 19 + jj;
        const float avg = sum / (float)L;
        mx = fminf(fmaxf(mx, 1e-9f), 1e9f);
        mn = fminf(fmaxf(mn, 1e-9f), 1e9f);
        const size_t base = (size_t)b * H;
        hf[base + j] = avg;             hb[base + j] = f2bf(avg);
        hf[base + DFEAT + j] = mx;      hb[base + DFEAT + j] = f2bf(mx);
        hf[base + 2 * DFEAT + j] = mn;  hb[base + 2 * DFEAT + j] = f2bf(mn);
        hf[base + 3 * DFEAT + j] = nxt; hb[base + 3 * DFEAT + j] = f2bf(nxt);
    }
}

// ---------------- embed-feature kernel: 32-lane group per row ----------------
__global__ __launch_bounds__(256)
void embfeat_kernel(const int* __restrict__ ids, const int* __restrict__ len,
                    const float* __restrict__ embed,
                    float* __restrict__ hf, ushort_t* __restrict__ hb) {
    const int x = threadIdx.x & 31;
    const int row = (blockIdx.x * 256 + threadIdx.x) >> 5;
    if (row >= B_SZ) return;
    const int L = len[row];
    const int* idrow = ids + (size_t)row * SEQ;
    const bool act = x < EMB;
    float sum = 0.f, mx = -3.0e38f, mn = 3.0e38f, nxt = 0.f;
#pragma unroll 5
    for (int s = 0; s < SEQ; ++s) {
        const int id = idrow[s];
        const float v = act ? embed[(size_t)id * EMB + x] : 0.f;
        if (s < L) { sum += v; mx = fmaxf(mx, v); mn = fminf(mn, v); }
        if (s == SEQ - 1) nxt = v;
    }
    if (act) {
        const float avg = sum / (float)L;
        mx = fminf(fmaxf(mx, 1e-9f), 1e9f);
        mn = fminf(fmaxf(mn, 1e-9f), 1e9f);
        const size_t base = (size_t)row * H;
        hf[base + x] = avg;             hb[base + x] = f2bf(avg);
        hf[base + DFEAT + x] = mx;      hb[base + DFEAT + x] = f2bf(mx);
        hf[base + 2 * DFEAT + x] = mn;  hb[base + 2 * DFEAT + x] = f2bf(mn);
        hf[base + 3 * DFEAT + x] = nxt; hb[base + 3 * DFEAT + x] = f2bf(nxt);
    }
}

// ---------------- GEMM: C = relu(A(MxK) * Bt(NxK)^T + bias) ----------------
// 128x128 tile, BK=64, 4 waves, single-buffered (m97-class structure;
// cross-block wave overlap at ~3 blocks/CU does the latency hiding).
// MODE 0: write bf16 out. MODE 1: hf += relu(...); hb = bf16(hf)
template <int MODE>
__global__ __launch_bounds__(256, 2)
void gemm_kernel(const ushort_t* __restrict__ A, const ushort_t* __restrict__ Bt,
                 const float* __restrict__ bias,
                 ushort_t* __restrict__ outBf,
                 float* __restrict__ hf, ushort_t* __restrict__ hb,
                 int M, int N, int K) {
    __shared__ alignas(16) ushort_t lA[128 * 64];
    __shared__ alignas(16) ushort_t lB[128 * 64];
    const int tid = threadIdx.x;
    const int lane = tid & 63;
    const int w = tid >> 6;
    const int wm = w >> 1, wn = w & 1;
    const int mtile = blockIdx.y, ntile = blockIdx.x;
    const ushort_t* Abase = A + (size_t)mtile * 128 * K;
    const ushort_t* Bbase = Bt + (size_t)ntile * 128 * K;

    f32x4 acc[4][4];
#pragma unroll
    for (int a = 0; a < 4; ++a)
#pragma unroll
        for (int b = 0; b < 4; ++b) acc[a][b] = (f32x4)(0.f);

    const int l3 = lane >> 3;          // row within 8-row staging group
    const int cl = (lane & 7) ^ l3;    // pre-swizzled source 16B column
    const int frow = lane & 15;        // fragment row/col within 16
    const int k16b = lane >> 4;        // fragment 16B k-slot base (0..3)

    const int nkt = K >> 6;
    for (int kt = 0; kt < nkt; ++kt) {
#pragma unroll
        for (int it = 0; it < 4; ++it) {
            const int row = w * 32 + it * 8 + l3;
            const ushort_t* ga = Abase + (size_t)row * K + kt * 64 + cl * 8;
            const ushort_t* gb = Bbase + (size_t)row * K + kt * 64 + cl * 8;
            __builtin_amdgcn_global_load_lds(
                (const __attribute__((address_space(1))) void*)ga,
                (__attribute__((address_space(3))) void*)(lA + (w * 32 + it * 8) * 64),
                16, 0, 0);
            __builtin_amdgcn_global_load_lds(
                (const __attribute__((address_space(1))) void*)gb,
                (__attribute__((address_space(3))) void*)(lB + (w * 32 + it * 8) * 64),
                16, 0, 0);
        }
        asm volatile("s_waitcnt vmcnt(0)" ::: "memory");
        __syncthreads();

        bf16x8 af[4][2], bfg[4][2];
#pragma unroll
        for (int mf = 0; mf < 4; ++mf)
#pragma unroll
            for (int ks = 0; ks < 2; ++ks) {
                const int row = wm * 64 + mf * 16 + frow;
                const int c = (ks * 4 + k16b) ^ (row & 7);
                af[mf][ks] = *(const bf16x8*)(lA + row * 64 + c * 8);
            }
#pragma unroll
        for (int nf = 0; nf < 4; ++nf)
#pragma unroll
            for (int ks = 0; ks < 2; ++ks) {
                const int row = wn * 64 + nf * 16 + frow;
                const int c = (ks * 4 + k16b) ^ (row & 7);
                bfg[nf][ks] = *(const bf16x8*)(lB + row * 64 + c * 8);
            }
#pragma unroll
        for (int mf = 0; mf < 4; ++mf)
#pragma unroll
            for (int nf = 0; nf < 4; ++nf)
#pragma unroll
                for (int ks = 0; ks < 2; ++ks)
                    acc[mf][nf] = __builtin_amdgcn_mfma_f32_16x16x32_bf16(
                        af[mf][ks], bfg[nf][ks], acc[mf][nf], 0, 0, 0);
        __syncthreads();
    }

    // epilogue
#pragma unroll
    for (int mf = 0; mf < 4; ++mf)
#pragma unroll
        for (int nf = 0; nf < 4; ++nf) {
            const int row0 = mtile * 128 + wm * 64 + mf * 16 + (lane >> 4) * 4;
            const int col = ntile * 128 + wn * 64 + nf * 16 + (lane & 15);
            const float bcol = bias[col];
#pragma unroll
            for (int jj = 0; jj < 4; ++jj) {
                float v = acc[mf][nf][jj] + bcol;
                v = v > 0.f ? v : 0.f;
                const size_t idx = (size_t)(row0 + jj) * N + col;
                if (MODE == 0) {
                    outBf[idx] = f2bf(v);
                } else {
                    float nh = hf[idx] + v;
                    hf[idx] = nh;
                    hb[idx] = f2bf(nh);
                }
            }
        }
}

// ---------------- final head: out = hf * Wf + bf ----------------
__global__ __launch_bounds__(256)
void final_kernel(const float* __restrict__ hf, const float* __restrict__ Wf,
                  const float* __restrict__ bfv, float* __restrict__ out) {
    const int gid = blockIdx.x * 256 + threadIdx.x;
    if (gid >= B_SZ * OUTD) return;
    const int b = gid / OUTD, o = gid % OUTD;
    const float* hrow = hf + (size_t)b * H;
    float acc = bfv[o];
    for (int k = 0; k < H; ++k) acc += hrow[k] * Wf[k * OUTD + o];
    out[gid] = acc;
}

extern "C" void kernel_launch(void* const* d_in, const int* in_sizes, int n_in,
                              void* d_out, int out_size, void* d_ws, size_t ws_size,
                              hipStream_t stream) {
    const float* inp   = (const float*)d_in[0];
    const int*   mask  = (const int*)d_in[1];
    const float* embed = (const float*)d_in[2];
    const float* W1    = (const float*)d_in[3];
    const float* b1    = (const float*)d_in[4];
    const float* W2    = (const float*)d_in[5];
    const float* b2    = (const float*)d_in[6];
    const float* Wf    = (const float*)d_in[7];
    const float* bfv   = (const float*)d_in[8];
    float* out = (float*)d_out;

    char* ws = (char*)d_ws;
    ushort_t* W1t = (ushort_t*)ws;                         // NBLK*H4*H bf16
    ushort_t* W2t = W1t + (size_t)NBLK * H4 * H;           // NBLK*H*H4 bf16
    float*    hf  = (float*)(W2t + (size_t)NBLK * H * H4); // B*H f32
    ushort_t* hb  = (ushort_t*)(hf + (size_t)B_SZ * H);    // B*H bf16
    ushort_t* T   = hb + (size_t)B_SZ * H;                 // B*H4 bf16 (GEMM1 out)
    // ids/len alias T's storage: consumed before the first GEMM writes T.
    int* ids = (int*)T;                                    // B*SEQ int
    int* lenb = ids + (size_t)B_SZ * SEQ;                  // B int

    transpose_bf16_kernel<<<dim3(H4 / 32, H / 32, NBLK), dim3(32, 8), 0, stream>>>(W1, W1t, H, H4);
    transpose_bf16_kernel<<<dim3(H / 32, H4 / 32, NBLK), dim3(32, 8), 0, stream>>>(W2, W2t, H4, H);

    len_kernel<<<(B_SZ * 64 + 255) / 256, 256, 0, stream>>>(mask, lenb);
    rawfeat_kernel<<<B_SZ, 128, 0, stream>>>(inp, lenb, hf, hb, ids);
    embfeat_kernel<<<(B_SZ * 32 + 255) / 256, 256, 0, stream>>>(ids, lenb, embed, hf, hb);

    for (int i = 0; i < NBLK; ++i) {
        gemm_kernel<0><<<dim3(H4 / 128, B_SZ / 128), 256, 0, stream>>>(
            hb, W1t + (size_t)i * H4 * H, b1 + (size_t)i * H4, T, nullptr, nullptr,
            B_SZ, H4, H);
        gemm_kernel<1><<<dim3(H / 128, B_SZ / 128), 256, 0, stream>>>(
            T, W2t + (size_t)i * H * H4, b2 + (size_t)i * H, nullptr, hf, hb,
            B_SZ, H, H4);
    }

    final_kernel<<<(B_SZ * OUTD + 255) / 256, 256, 0, stream>>>(hf, Wf, bfv, out);
}

// Round 6
// 1311.782 us; speedup vs baseline: 1.3415x; 1.0282x over previous
//
#include <hip/hip_runtime.h>
#include <stdint.h>

typedef unsigned short ushort_t;
typedef __attribute__((ext_vector_type(8))) __bf16 bf16x8;
typedef __attribute__((ext_vector_type(4))) float f32x4;

#define B_SZ 16384
#define SEQ 50
#define RAWF 109
#define EMB 20
#define DFEAT 128
#define H 512
#define H4 2048
#define NBLK 10
#define OUTD 20

__device__ __forceinline__ ushort_t f2bf(float f) {
    union { float f; uint32_t u; } v; v.f = f;
    uint32_t r = (v.u + 0x7fffu + ((v.u >> 16) & 1u)) >> 16;
    return (ushort_t)r;
}

// ---------------- weight transpose + bf16 convert ----------------
__global__ __launch_bounds__(256)
void transpose_bf16_kernel(const float* __restrict__ src, ushort_t* __restrict__ dst,
                           int K, int N) {
    __shared__ float tile[32][33];
    const int i = blockIdx.z;
    const float* s = src + (size_t)i * K * N;
    ushort_t* d = dst + (size_t)i * K * N;
    const int tx = threadIdx.x, ty = threadIdx.y; // 32 x 8
    const int k0 = blockIdx.y * 32, n0 = blockIdx.x * 32;
#pragma unroll
    for (int r = 0; r < 4; ++r)
        tile[ty + r * 8][tx] = s[(size_t)(k0 + ty + r * 8) * N + n0 + tx];
    __syncthreads();
#pragma unroll
    for (int r = 0; r < 4; ++r) {
        int n = ty + r * 8;
        d[(size_t)(n0 + n) * K + k0 + tx] = f2bf(tile[tx][n]);
    }
}

// ---------------- seq-len kernel: wave per row ----------------
__global__ __launch_bounds__(256)
void len_kernel(const int* __restrict__ mask, int* __restrict__ len) {
    const int wid = (blockIdx.x * 256 + threadIdx.x) >> 6;
    const int lane = threadIdx.x & 63;
    if (wid >= B_SZ) return;
    int c = (lane < SEQ) ? mask[(size_t)wid * SEQ + lane] : 0;
#pragma unroll
    for (int off = 32; off > 0; off >>= 1) c += __shfl_down(c, off);
    c = __shfl(c, 0);
    if (lane == 0) len[wid] = c;
}

// ---------------- raw-feature kernel: thread = one input column ----------------
__global__ __launch_bounds__(128)
void rawfeat_kernel(const float* __restrict__ inp, const int* __restrict__ len,
                    float* __restrict__ hf, ushort_t* __restrict__ hb,
                    int* __restrict__ ids) {
    const int b = blockIdx.x;
    const int jj = threadIdx.x;
    const float* src = inp + (size_t)b * SEQ * RAWF;
    const int L = len[b];
    const bool active = jj < RAWF;
    float sum = 0.f, mx = -3.0e38f, mn = 3.0e38f, nxt = 0.f;
#pragma unroll 5
    for (int s = 0; s < SEQ; ++s) {
        float v = active ? src[s * RAWF + jj] : 0.f;
        if (s < L) { sum += v; mx = fmaxf(mx, v); mn = fminf(mn, v); }
        if (s == SEQ - 1) nxt = v;
        if (jj == 0) ids[(size_t)b * SEQ + s] = (int)v;
    }
    if (jj >= 1 && jj < RAWF) {
        const int j = 19 + jj;
        const float avg = sum / (float)L;
        mx = fminf(fmaxf(mx, 1e-9f), 1e9f);
        mn = fminf(fmaxf(mn, 1e-9f), 1e9f);
        const size_t base = (size_t)b * H;
        hf[base + j] = avg;             hb[base + j] = f2bf(avg);
        hf[base + DFEAT + j] = mx;      hb[base + DFEAT + j] = f2bf(mx);
        hf[base + 2 * DFEAT + j] = mn;  hb[base + 2 * DFEAT + j] = f2bf(mn);
        hf[base + 3 * DFEAT + j] = nxt; hb[base + 3 * DFEAT + j] = f2bf(nxt);
    }
}

// ---------------- embed-feature kernel: 32-lane group per row ----------------
__global__ __launch_bounds__(256)
void embfeat_kernel(const int* __restrict__ ids, const int* __restrict__ len,
                    const float* __restrict__ embed,
                    float* __restrict__ hf, ushort_t* __restrict__ hb) {
    const int x = threadIdx.x & 31;
    const int row = (blockIdx.x * 256 + threadIdx.x) >> 5;
    if (row >= B_SZ) return;
    const int L = len[row];
    const int* idrow = ids + (size_t)row * SEQ;
    const bool act = x < EMB;
    float sum = 0.f, mx = -3.0e38f, mn = 3.0e38f, nxt = 0.f;
#pragma unroll 5
    for (int s = 0; s < SEQ; ++s) {
        const int id = idrow[s];
        const float v = act ? embed[(size_t)id * EMB + x] : 0.f;
        if (s < L) { sum += v; mx = fmaxf(mx, v); mn = fminf(mn, v); }
        if (s == SEQ - 1) nxt = v;
    }
    if (act) {
        const float avg = sum / (float)L;
        mx = fminf(fmaxf(mx, 1e-9f), 1e9f);
        mn = fminf(fmaxf(mn, 1e-9f), 1e9f);
        const size_t base = (size_t)row * H;
        hf[base + x] = avg;             hb[base + x] = f2bf(avg);
        hf[base + DFEAT + x] = mx;      hb[base + DFEAT + x] = f2bf(mx);
        hf[base + 2 * DFEAT + x] = mn;  hb[base + 2 * DFEAT + x] = f2bf(mn);
        hf[base + 3 * DFEAT + x] = nxt; hb[base + 3 * DFEAT + x] = f2bf(nxt);
    }
}

// ---------------- GEMM: C = relu(A(MxK) * Bt(NxK)^T + bias) ----------------
// 128x128 tile, BK=64, 4 waves, single-buffered m97-class structure.
// __launch_bounds__(256,3): cap VGPR ~170 -> 3 blocks/CU (m97 occupancy);
// cross-block wave overlap is the latency-hiding mechanism (m114).
// MODE 0: write bf16 out. MODE 1: hf += relu(...); hb = bf16(hf)
template <int MODE>
__global__ __launch_bounds__(256, 3)
void gemm_kernel(const ushort_t* __restrict__ A, const ushort_t* __restrict__ Bt,
                 const float* __restrict__ bias,
                 ushort_t* __restrict__ outBf,
                 float* __restrict__ hf, ushort_t* __restrict__ hb,
                 int M, int N, int K) {
    __shared__ alignas(16) ushort_t lA[128 * 64];
    __shared__ alignas(16) ushort_t lB[128 * 64];
    const int tid = threadIdx.x;
    const int lane = tid & 63;
    const int w = tid >> 6;
    const int wm = w >> 1, wn = w & 1;

    // XCD-aware bijective swizzle over the flattened grid (nwg % 8 == 0)
    const int gx = N >> 7;                 // ntiles
    const int nwg = (M >> 7) * gx;
    const int cpx = nwg >> 3;
    const int bid = blockIdx.x;
    const int wg = (bid & 7) * cpx + (bid >> 3);
    const int ntile = wg % gx, mtile = wg / gx;

    const ushort_t* Abase = A + (size_t)mtile * 128 * K;
    const ushort_t* Bbase = Bt + (size_t)ntile * 128 * K;

    f32x4 acc[4][4];
#pragma unroll
    for (int a = 0; a < 4; ++a)
#pragma unroll
        for (int b = 0; b < 4; ++b) acc[a][b] = (f32x4)(0.f);

    const int l3 = lane >> 3;          // row within 8-row staging group
    const int cl = (lane & 7) ^ l3;    // pre-swizzled source 16B column
    const int frow = lane & 15;        // fragment row/col within 16
    const int k16b = lane >> 4;        // fragment 16B k-slot base (0..3)

    const int nkt = K >> 6;
    for (int kt = 0; kt < nkt; ++kt) {
#pragma unroll
        for (int it = 0; it < 4; ++it) {
            const int row = w * 32 + it * 8 + l3;
            const ushort_t* ga = Abase + (size_t)row * K + kt * 64 + cl * 8;
            const ushort_t* gb = Bbase + (size_t)row * K + kt * 64 + cl * 8;
            __builtin_amdgcn_global_load_lds(
                (const __attribute__((address_space(1))) void*)ga,
                (__attribute__((address_space(3))) void*)(lA + (w * 32 + it * 8) * 64),
                16, 0, 0);
            __builtin_amdgcn_global_load_lds(
                (const __attribute__((address_space(1))) void*)gb,
                (__attribute__((address_space(3))) void*)(lB + (w * 32 + it * 8) * 64),
                16, 0, 0);
        }
        asm volatile("s_waitcnt vmcnt(0)" ::: "memory");
        __syncthreads();

        bf16x8 af[4][2], bfg[4][2];
#pragma unroll
        for (int mf = 0; mf < 4; ++mf)
#pragma unroll
            for (int ks = 0; ks < 2; ++ks) {
                const int row = wm * 64 + mf * 16 + frow;
                const int c = (ks * 4 + k16b) ^ (row & 7);
                af[mf][ks] = *(const bf16x8*)(lA + row * 64 + c * 8);
            }
#pragma unroll
        for (int nf = 0; nf < 4; ++nf)
#pragma unroll
            for (int ks = 0; ks < 2; ++ks) {
                const int row = wn * 64 + nf * 16 + frow;
                const int c = (ks * 4 + k16b) ^ (row & 7);
                bfg[nf][ks] = *(const bf16x8*)(lB + row * 64 + c * 8);
            }
#pragma unroll
        for (int mf = 0; mf < 4; ++mf)
#pragma unroll
            for (int nf = 0; nf < 4; ++nf)
#pragma unroll
                for (int ks = 0; ks < 2; ++ks)
                    acc[mf][nf] = __builtin_amdgcn_mfma_f32_16x16x32_bf16(
                        af[mf][ks], bfg[nf][ks], acc[mf][nf], 0, 0, 0);
        __syncthreads();
    }

    // epilogue
#pragma unroll
    for (int mf = 0; mf < 4; ++mf)
#pragma unroll
        for (int nf = 0; nf < 4; ++nf) {
            const int row0 = mtile * 128 + wm * 64 + mf * 16 + (lane >> 4) * 4;
            const int col = ntile * 128 + wn * 64 + nf * 16 + (lane & 15);
            const float bcol = bias[col];
#pragma unroll
            for (int jj = 0; jj < 4; ++jj) {
                float v = acc[mf][nf][jj] + bcol;
                v = v > 0.f ? v : 0.f;
                const size_t idx = (size_t)(row0 + jj) * N + col;
                if (MODE == 0) {
                    outBf[idx] = f2bf(v);
                } else {
                    float nh = hf[idx] + v;
                    hf[idx] = nh;
                    hb[idx] = f2bf(nh);
                }
            }
        }
}

// ---------------- final head: out = hf * Wf + bf ----------------
__global__ __launch_bounds__(256)
void final_kernel(const float* __restrict__ hf, const float* __restrict__ Wf,
                  const float* __restrict__ bfv, float* __restrict__ out) {
    const int gid = blockIdx.x * 256 + threadIdx.x;
    if (gid >= B_SZ * OUTD) return;
    const int b = gid / OUTD, o = gid % OUTD;
    const float* hrow = hf + (size_t)b * H;
    float acc = bfv[o];
    for (int k = 0; k < H; ++k) acc += hrow[k] * Wf[k * OUTD + o];
    out[gid] = acc;
}

extern "C" void kernel_launch(void* const* d_in, const int* in_sizes, int n_in,
                              void* d_out, int out_size, void* d_ws, size_t ws_size,
                              hipStream_t stream) {
    const float* inp   = (const float*)d_in[0];
    const int*   mask  = (const int*)d_in[1];
    const float* embed = (const float*)d_in[2];
    const float* W1    = (const float*)d_in[3];
    const float* b1    = (const float*)d_in[4];
    const float* W2    = (const float*)d_in[5];
    const float* b2    = (const float*)d_in[6];
    const float* Wf    = (const float*)d_in[7];
    const float* bfv   = (const float*)d_in[8];
    float* out = (float*)d_out;

    char* ws = (char*)d_ws;
    ushort_t* W1t = (ushort_t*)ws;                         // NBLK*H4*H bf16
    ushort_t* W2t = W1t + (size_t)NBLK * H4 * H;           // NBLK*H*H4 bf16
    float*    hf  = (float*)(W2t + (size_t)NBLK * H * H4); // B*H f32
    ushort_t* hb  = (ushort_t*)(hf + (size_t)B_SZ * H);    // B*H bf16
    ushort_t* T   = hb + (size_t)B_SZ * H;                 // B*H4 bf16 (GEMM1 out)
    // ids/len alias T's storage: consumed before the first GEMM writes T.
    int* ids = (int*)T;                                    // B*SEQ int
    int* lenb = ids + (size_t)B_SZ * SEQ;                  // B int

    transpose_bf16_kernel<<<dim3(H4 / 32, H / 32, NBLK), dim3(32, 8), 0, stream>>>(W1, W1t, H, H4);
    transpose_bf16_kernel<<<dim3(H / 32, H4 / 32, NBLK), dim3(32, 8), 0, stream>>>(W2, W2t, H4, H);

    len_kernel<<<(B_SZ * 64 + 255) / 256, 256, 0, stream>>>(mask, lenb);
    rawfeat_kernel<<<B_SZ, 128, 0, stream>>>(inp, lenb, hf, hb, ids);
    embfeat_kernel<<<(B_SZ * 32 + 255) / 256, 256, 0, stream>>>(ids, lenb, embed, hf, hb);

    for (int i = 0; i < NBLK; ++i) {
        gemm_kernel<0><<<(B_SZ / 128) * (H4 / 128), 256, 0, stream>>>(
            hb, W1t + (size_t)i * H4 * H, b1 + (size_t)i * H4, T, nullptr, nullptr,
            B_SZ, H4, H);
        gemm_kernel<1><<<(B_SZ / 128) * (H / 128), 256, 0, stream>>>(
            T, W2t + (size_t)i * H * H4, b2 + (size_t)i * H, nullptr, hf, hb,
            B_SZ, H, H4);
    }

    final_kernel<<<(B_SZ * OUTD + 255) / 256, 256, 0, stream>>>(hf, Wf, bfv, out);
}

// Round 7
// 1306.112 us; speedup vs baseline: 1.3474x; 1.0043x over previous
//
#include <hip/hip_runtime.h>
#include <stdint.h>

typedef unsigned short ushort_t;
typedef __attribute__((ext_vector_type(8))) __bf16 bf16x8;
typedef __attribute__((ext_vector_type(4))) float f32x4;

#define B_SZ 16384
#define SEQ 50
#define RAWF 109
#define EMB 20
#define DFEAT 128
#define H 512
#define H4 2048
#define NBLK 10
#define OUTD 20

__device__ __forceinline__ ushort_t f2bf(float f) {
    union { float f; uint32_t u; } v; v.f = f;
    uint32_t r = (v.u + 0x7fffu + ((v.u >> 16) & 1u)) >> 16;
    return (ushort_t)r;
}

// ---------------- weight transpose + bf16 convert (vectorized) ----------------
// src: NBLK matrices (K x N) f32 -> dst: (N x K) bf16. 64x64 tiles.
// Reads float4 (16B/lane), writes ushort4 (8B/lane); LDS tile 64x65 keeps
// both phases at <=2-way bank aliasing (free per m136).
__global__ __launch_bounds__(256)
void transpose_bf16_kernel(const float* __restrict__ src, ushort_t* __restrict__ dst,
                           int K, int N) {
    __shared__ float tile[64][65];
    const int i = blockIdx.z;
    const float* s = src + (size_t)i * K * N;
    ushort_t* d = dst + (size_t)i * K * N;
    const int t = threadIdx.x;
    const int rr = t >> 4;      // 0..15
    const int cc = t & 15;      // 0..15
    const int k0 = blockIdx.y * 64, n0 = blockIdx.x * 64;
#pragma unroll
    for (int r = 0; r < 4; ++r) {
        const int kr = rr + r * 16;
        const float4 v = *(const float4*)(s + (size_t)(k0 + kr) * N + n0 + cc * 4);
        tile[kr][cc * 4 + 0] = v.x;
        tile[kr][cc * 4 + 1] = v.y;
        tile[kr][cc * 4 + 2] = v.z;
        tile[kr][cc * 4 + 3] = v.w;
    }
    __syncthreads();
#pragma unroll
    for (int r = 0; r < 4; ++r) {
        const int nr = rr + r * 16;
        ushort4 o;
        o.x = f2bf(tile[cc * 4 + 0][nr]);
        o.y = f2bf(tile[cc * 4 + 1][nr]);
        o.z = f2bf(tile[cc * 4 + 2][nr]);
        o.w = f2bf(tile[cc * 4 + 3][nr]);
        *(ushort4*)(d + (size_t)(n0 + nr) * K + k0 + cc * 4) = o;
    }
}

// ---------------- seq-len kernel: wave per row ----------------
__global__ __launch_bounds__(256)
void len_kernel(const int* __restrict__ mask, int* __restrict__ len) {
    const int wid = (blockIdx.x * 256 + threadIdx.x) >> 6;
    const int lane = threadIdx.x & 63;
    if (wid >= B_SZ) return;
    int c = (lane < SEQ) ? mask[(size_t)wid * SEQ + lane] : 0;
#pragma unroll
    for (int off = 32; off > 0; off >>= 1) c += __shfl_down(c, off);
    c = __shfl(c, 0);
    if (lane == 0) len[wid] = c;
}

// ---------------- raw-feature kernel: thread = one input column ----------------
__global__ __launch_bounds__(128)
void rawfeat_kernel(const float* __restrict__ inp, const int* __restrict__ len,
                    float* __restrict__ hf, ushort_t* __restrict__ hb,
                    int* __restrict__ ids) {
    const int b = blockIdx.x;
    const int jj = threadIdx.x;
    const float* src = inp + (size_t)b * SEQ * RAWF;
    const int L = len[b];
    const bool active = jj < RAWF;
    float sum = 0.f, mx = -3.0e38f, mn = 3.0e38f, nxt = 0.f;
#pragma unroll 10
    for (int s = 0; s < SEQ; ++s) {
        float v = active ? src[s * RAWF + jj] : 0.f;
        if (s < L) { sum += v; mx = fmaxf(mx, v); mn = fminf(mn, v); }
        if (s == SEQ - 1) nxt = v;
        if (jj == 0) ids[(size_t)b * SEQ + s] = (int)v;
    }
    if (jj >= 1 && jj < RAWF) {
        const int j = 19 + jj;
        const float avg = sum / (float)L;
        mx = fminf(fmaxf(mx, 1e-9f), 1e9f);
        mn = fminf(fmaxf(mn, 1e-9f), 1e9f);
        const size_t base = (size_t)b * H;
        hf[base + j] = avg;             hb[base + j] = f2bf(avg);
        hf[base + DFEAT + j] = mx;      hb[base + DFEAT + j] = f2bf(mx);
        hf[base + 2 * DFEAT + j] = mn;  hb[base + 2 * DFEAT + j] = f2bf(mn);
        hf[base + 3 * DFEAT + j] = nxt; hb[base + 3 * DFEAT + j] = f2bf(nxt);
    }
}

// ---------------- embed-feature kernel: 32-lane group per row ----------------
__global__ __launch_bounds__(256)
void embfeat_kernel(const int* __restrict__ ids, const int* __restrict__ len,
                    const float* __restrict__ embed,
                    float* __restrict__ hf, ushort_t* __restrict__ hb) {
    const int x = threadIdx.x & 31;
    const int row = (blockIdx.x * 256 + threadIdx.x) >> 5;
    if (row >= B_SZ) return;
    const int L = len[row];
    const int* idrow = ids + (size_t)row * SEQ;
    const bool act = x < EMB;
    float sum = 0.f, mx = -3.0e38f, mn = 3.0e38f, nxt = 0.f;
#pragma unroll 10
    for (int s = 0; s < SEQ; ++s) {
        const int id = idrow[s];
        const float v = act ? embed[(size_t)id * EMB + x] : 0.f;
        if (s < L) { sum += v; mx = fmaxf(mx, v); mn = fminf(mn, v); }
        if (s == SEQ - 1) nxt = v;
    }
    if (act) {
        const float avg = sum / (float)L;
        mx = fminf(fmaxf(mx, 1e-9f), 1e9f);
        mn = fminf(fmaxf(mn, 1e-9f), 1e9f);
        const size_t base = (size_t)row * H;
        hf[base + x] = avg;             hb[base + x] = f2bf(avg);
        hf[base + DFEAT + x] = mx;      hb[base + DFEAT + x] = f2bf(mx);
        hf[base + 2 * DFEAT + x] = mn;  hb[base + 2 * DFEAT + x] = f2bf(mn);
        hf[base + 3 * DFEAT + x] = nxt; hb[base + 3 * DFEAT + x] = f2bf(nxt);
    }
}

// ---------------- GEMM: C = relu(A(MxK) * Bt(NxK)^T + bias) ----------------
// 128x128 tile, BK=64, 4 waves, single-buffered m97-class structure.
// MODE 0: write bf16 out. MODE 1: hf += relu(...); hb = bf16(hf)
template <int MODE>
__global__ __launch_bounds__(256, 3)
void gemm_kernel(const ushort_t* __restrict__ A, const ushort_t* __restrict__ Bt,
                 const float* __restrict__ bias,
                 ushort_t* __restrict__ outBf,
                 float* __restrict__ hf, ushort_t* __restrict__ hb,
                 int M, int N, int K) {
    __shared__ alignas(16) ushort_t lA[128 * 64];
    __shared__ alignas(16) ushort_t lB[128 * 64];
    const int tid = threadIdx.x;
    const int lane = tid & 63;
    const int w = tid >> 6;
    const int wm = w >> 1, wn = w & 1;

    // XCD-aware bijective swizzle over the flattened grid (nwg % 8 == 0)
    const int gx = N >> 7;                 // ntiles
    const int nwg = (M >> 7) * gx;
    const int cpx = nwg >> 3;
    const int bid = blockIdx.x;
    const int wg = (bid & 7) * cpx + (bid >> 3);
    const int ntile = wg % gx, mtile = wg / gx;

    const ushort_t* Abase = A + (size_t)mtile * 128 * K;
    const ushort_t* Bbase = Bt + (size_t)ntile * 128 * K;

    f32x4 acc[4][4];
#pragma unroll
    for (int a = 0; a < 4; ++a)
#pragma unroll
        for (int b = 0; b < 4; ++b) acc[a][b] = (f32x4)(0.f);

    const int l3 = lane >> 3;          // row within 8-row staging group
    const int cl = (lane & 7) ^ l3;    // pre-swizzled source 16B column
    const int frow = lane & 15;        // fragment row/col within 16
    const int k16b = lane >> 4;        // fragment 16B k-slot base (0..3)

    const int nkt = K >> 6;
    for (int kt = 0; kt < nkt; ++kt) {
#pragma unroll
        for (int it = 0; it < 4; ++it) {
            const int row = w * 32 + it * 8 + l3;
            const ushort_t* ga = Abase + (size_t)row * K + kt * 64 + cl * 8;
            const ushort_t* gb = Bbase + (size_t)row * K + kt * 64 + cl * 8;
            __builtin_amdgcn_global_load_lds(
                (const __attribute__((address_space(1))) void*)ga,
                (__attribute__((address_space(3))) void*)(lA + (w * 32 + it * 8) * 64),
                16, 0, 0);
            __builtin_amdgcn_global_load_lds(
                (const __attribute__((address_space(1))) void*)gb,
                (__attribute__((address_space(3))) void*)(lB + (w * 32 + it * 8) * 64),
                16, 0, 0);
        }
        asm volatile("s_waitcnt vmcnt(0)" ::: "memory");
        __syncthreads();

        bf16x8 af[4][2], bfg[4][2];
#pragma unroll
        for (int mf = 0; mf < 4; ++mf)
#pragma unroll
            for (int ks = 0; ks < 2; ++ks) {
                const int row = wm * 64 + mf * 16 + frow;
                const int c = (ks * 4 + k16b) ^ (row & 7);
                af[mf][ks] = *(const bf16x8*)(lA + row * 64 + c * 8);
            }
#pragma unroll
        for (int nf = 0; nf < 4; ++nf)
#pragma unroll
            for (int ks = 0; ks < 2; ++ks) {
                const int row = wn * 64 + nf * 16 + frow;
                const int c = (ks * 4 + k16b) ^ (row & 7);
                bfg[nf][ks] = *(const bf16x8*)(lB + row * 64 + c * 8);
            }
#pragma unroll
        for (int mf = 0; mf < 4; ++mf)
#pragma unroll
            for (int nf = 0; nf < 4; ++nf)
#pragma unroll
                for (int ks = 0; ks < 2; ++ks)
                    acc[mf][nf] = __builtin_amdgcn_mfma_f32_16x16x32_bf16(
                        af[mf][ks], bfg[nf][ks], acc[mf][nf], 0, 0, 0);
        __syncthreads();
    }

    // epilogue
#pragma unroll
    for (int mf = 0; mf < 4; ++mf)
#pragma unroll
        for (int nf = 0; nf < 4; ++nf) {
            const int row0 = mtile * 128 + wm * 64 + mf * 16 + (lane >> 4) * 4;
            const int col = ntile * 128 + wn * 64 + nf * 16 + (lane & 15);
            const float bcol = bias[col];
#pragma unroll
            for (int jj = 0; jj < 4; ++jj) {
                float v = acc[mf][nf][jj] + bcol;
                v = v > 0.f ? v : 0.f;
                const size_t idx = (size_t)(row0 + jj) * N + col;
                if (MODE == 0) {
                    outBf[idx] = f2bf(v);
                } else {
                    float nh = hf[idx] + v;
                    hf[idx] = nh;
                    hb[idx] = f2bf(nh);
                }
            }
        }
}

// ---------------- final head: out = hf * Wf + bf ----------------
__global__ __launch_bounds__(256)
void final_kernel(const float* __restrict__ hf, const float* __restrict__ Wf,
                  const float* __restrict__ bfv, float* __restrict__ out) {
    const int gid = blockIdx.x * 256 + threadIdx.x;
    if (gid >= B_SZ * OUTD) return;
    const int b = gid / OUTD, o = gid % OUTD;
    const float* hrow = hf + (size_t)b * H;
    float acc = bfv[o];
    for (int k = 0; k < H; ++k) acc += hrow[k] * Wf[k * OUTD + o];
    out[gid] = acc;
}

extern "C" void kernel_launch(void* const* d_in, const int* in_sizes, int n_in,
                              void* d_out, int out_size, void* d_ws, size_t ws_size,
                              hipStream_t stream) {
    const float* inp   = (const float*)d_in[0];
    const int*   mask  = (const int*)d_in[1];
    const float* embed = (const float*)d_in[2];
    const float* W1    = (const float*)d_in[3];
    const float* b1    = (const float*)d_in[4];
    const float* W2    = (const float*)d_in[5];
    const float* b2    = (const float*)d_in[6];
    const float* Wf    = (const float*)d_in[7];
    const float* bfv   = (const float*)d_in[8];
    float* out = (float*)d_out;

    char* ws = (char*)d_ws;
    ushort_t* W1t = (ushort_t*)ws;                         // NBLK*H4*H bf16
    ushort_t* W2t = W1t + (size_t)NBLK * H4 * H;           // NBLK*H*H4 bf16
    float*    hf  = (float*)(W2t + (size_t)NBLK * H * H4); // B*H f32
    ushort_t* hb  = (ushort_t*)(hf + (size_t)B_SZ * H);    // B*H bf16
    ushort_t* T   = hb + (size_t)B_SZ * H;                 // B*H4 bf16 (GEMM1 out)
    // ids/len alias T's storage: consumed before the first GEMM writes T.
    int* ids = (int*)T;                                    // B*SEQ int
    int* lenb = ids + (size_t)B_SZ * SEQ;                  // B int

    // W1[i]: (H x H4) -> W1t[i]: (H4 x H);  W2[i]: (H4 x H) -> W2t[i]: (H x H4)
    transpose_bf16_kernel<<<dim3(H4 / 64, H / 64, NBLK), 256, 0, stream>>>(W1, W1t, H, H4);
    transpose_bf16_kernel<<<dim3(H / 64, H4 / 64, NBLK), 256, 0, stream>>>(W2, W2t, H4, H);

    len_kernel<<<(B_SZ * 64 + 255) / 256, 256, 0, stream>>>(mask, lenb);
    rawfeat_kernel<<<B_SZ, 128, 0, stream>>>(inp, lenb, hf, hb, ids);
    embfeat_kernel<<<(B_SZ * 32 + 255) / 256, 256, 0, stream>>>(ids, lenb, embed, hf, hb);

    for (int i = 0; i < NBLK; ++i) {
        gemm_kernel<0><<<(B_SZ / 128) * (H4 / 128), 256, 0, stream>>>(
            hb, W1t + (size_t)i * H4 * H, b1 + (size_t)i * H4, T, nullptr, nullptr,
            B_SZ, H4, H);
        gemm_kernel<1><<<(B_SZ / 128) * (H / 128), 256, 0, stream>>>(
            T, W2t + (size_t)i * H * H4, b2 + (size_t)i * H, nullptr, hf, hb,
            B_SZ, H, H4);
    }

    final_kernel<<<(B_SZ * OUTD + 255) / 256, 256, 0, stream>>>(hf, Wf, bfv, out);
}